// Round 6
// baseline (182.062 us; speedup 1.0000x reference)
//
#include <hip/hip_runtime.h>

// Correlation layer: out[b,o,h,w] = mean_c x1[b,c,h,w] * x2[b,c,h+dh,w+dw]
// B=8 C=128 H=W=128, d=4 -> 81 offsets (o = (dh+4)*9 + (dw+4)).
//
// R8: 2 WGs/CU. R7 (73us) was lockstep-exposure-bound: 1 WG/CU meant the
// per-iteration serial chain (ds_write -> lgkm drain -> barrier -> DS-pipe
// serialized reads -> vmcnt(0) on first-touch HBM prefetch) was fully
// exposed (~1700 of 2737 cyc/iter with both pipes <40% busy).
// R8 keeps R7's 9-dh-waves-share-staged-rows design but tiles TH=2 rows ->
// grid 512 = 2 WGs/CU; one WG computes while the other drains its barrier.
//  - per-wave layout: 4 px/lane, 32 lanes span a 128-px row, r=lane>>5.
//    +-4 px halo == +-1 lane: wave_shr:1 / wave_shl:1 DPP (full-wave
//    shifts, ctrl 0x138/0x130; same direction convention validated in
//    R6/R7), with cndmask zero at the row seam (lh==0 / lh==31) since
//    lanes 32/31 would receive the other image row's pixels.
//  - acc[9] f4 = 36 regs -> ~80 VGPR; __launch_bounds__(576,5) so 5
//    waves/SIMD fit (18 waves/CU = 2 WGs).
//  - LDS: 12 rows (2 x1 + 10 x2) x 128 floats x 2ch-slab x 2buf = 24 KB.
//    Staging: threads 0..383, thread t -> row t>>5, f4 slot t&31, LDS
//    float offset 4t (linear; 16B-stride b128 writes/reads, 0 conflicts
//    per R7 measurement). OOB x2 rows stage zeros (pv stays 0).
//  - prefetch issued AFTER the barrier (hipcc drains vmcnt(0) before
//    s_barrier), consumed at next iter's ds_write.

constexpr int Cn = 128, Hn = 128, Wn = 128;
constexpr int HWn = Hn * Wn;
constexpr int TH = 2;
constexpr int NROWS = 12;           // 2 x1 rows + 10 x2 rows
constexpr int ROWF  = 128;          // floats per LDS row
constexpr int CHF   = NROWS * ROWF; // 1536 floats per channel slab
constexpr int BUFF  = 2 * CHF;      // buffer = 2 channel slabs

__device__ __forceinline__ float dpp_wshr1(float x) {  // lane i <- lane i-1 (lane0: 0)
  return __int_as_float(__builtin_amdgcn_update_dpp(
      0, __float_as_int(x), 0x138, 0xF, 0xF, true));
}
__device__ __forceinline__ float dpp_wshl1(float x) {  // lane i <- lane i+1 (lane63: 0)
  return __int_as_float(__builtin_amdgcn_update_dpp(
      0, __float_as_int(x), 0x130, 0xF, 0xF, true));
}

__global__ __launch_bounds__(576, 5)
void corr_kernel(const float* __restrict__ x1, const float* __restrict__ x2,
                 float* __restrict__ out) {
  __shared__ float lds[2][2][NROWS][ROWF];  // [buf][ch][row][float] ; 24 KB

  const int t    = threadIdx.x;  // 0..575
  const int w    = t >> 6;       // wave 0..8 -> dh = w-4
  const int lane = t & 63;
  const int r    = lane >> 5;    // output row 0..1
  const int lh   = lane & 31;    // px group: px 4lh..4lh+3

  const int phys = blockIdx.x;   // 0..511 (2 per CU)
  const int b    = phys & 7;     // batch == XCD (round-robin assumption)
  const int tile = phys >> 3;    // 0..63
  const int h0   = tile * TH;

  // ---- staging assignment (threads 0..383: one f4 per channel) ----
  const bool stg  = t < 384;
  const int ridx  = t >> 5;      // LDS row 0..11 (valid for t<384)
  const int s     = t & 31;      // f4 slot (px 4s..4s+3)
  int gr;
  bool okg;
  if (ridx < 2) { gr = h0 + ridx; okg = true; }                  // x1 rows
  else { gr = h0 + ridx - 6; okg = (unsigned)gr < (unsigned)Hn; } // x2 -4..+5
  okg = okg && stg;
  const float* src = (ridx < 2 ? x1 : x2) + (size_t)b * Cn * HWn
                   + (size_t)(okg ? gr : 0) * Wn + (s << 2);
  float* const L = &lds[0][0][0][0];
  const int woff = t << 2;       // float offset 4t within slab (linear)

  // ---- per-wave LDS read offsets (within slab) ----
  const int o1 = r * ROWF + (lh << 2);            // x1 row r
  const int o2 = (r + w + 2) * ROWF + (lh << 2);  // staged x2 row r+dh+6

  const bool lEdge = (lh == 0);
  const bool rEdge = (lh == 31);

  float4 acc[9];
#pragma unroll
  for (int dw = 0; dw < 9; ++dw) acc[dw] = make_float4(0.f, 0.f, 0.f, 0.f);

  // prologue: prefetch channels 0,1
  const float4 z4 = make_float4(0.f, 0.f, 0.f, 0.f);
  float4 pv0 = z4, pv1 = z4;
  if (okg) { pv0 = *(const float4*)src; pv1 = *(const float4*)(src + HWn); }
  src += 2 * HWn;

#pragma unroll 1
  for (int step = 0; step < 64; ++step) {
    const int bo = (step & 1) * BUFF;
    if (stg) {
      *(float4*)(L + bo + woff)       = pv0;   // channel 2*step
      *(float4*)(L + bo + CHF + woff) = pv1;   // channel 2*step+1
    }
    __syncthreads();
    // prefetch next slab AFTER the barrier; consumed at next ds_write
    if (okg && step < 63) {
      pv0 = *(const float4*)src;
      pv1 = *(const float4*)(src + HWn);
    }
    src += 2 * HWn;

#pragma unroll
    for (int ch = 0; ch < 2; ++ch) {
      const float* p = L + bo + ch * CHF;
      const float4 a  = *(const float4*)(p + o1);
      const float4 b0 = *(const float4*)(p + o2);
      // halo via full-wave DPP shifts; zero at the 32-lane row seam
      float Lx = dpp_wshr1(b0.x), Ly = dpp_wshr1(b0.y),
            Lz = dpp_wshr1(b0.z), Lw = dpp_wshr1(b0.w);
      float Rx = dpp_wshl1(b0.x), Ry = dpp_wshl1(b0.y),
            Rz = dpp_wshl1(b0.z), Rw = dpp_wshl1(b0.w);
      if (lEdge) { Lx = 0.f; Ly = 0.f; Lz = 0.f; Lw = 0.f; }
      if (rEdge) { Rx = 0.f; Ry = 0.f; Rz = 0.f; Rw = 0.f; }
      // win[k] = x2[px 4lh + k - 4], k = 0..11
      const float win[12] = {Lx, Ly, Lz, Lw,
                             b0.x, b0.y, b0.z, b0.w,
                             Rx, Ry, Rz, Rw};
#pragma unroll
      for (int dw = 0; dw < 9; ++dw) {
        acc[dw].x += a.x * win[dw + 0];
        acc[dw].y += a.y * win[dw + 1];
        acc[dw].z += a.z * win[dw + 2];
        acc[dw].w += a.w * win[dw + 3];
      }
    }
  }

  // ---- epilogue: scale + store (each wave owns its dh entirely) ----
  const float scale = 1.0f / 128.0f;
  float* ob = out + ((size_t)b * 81 + (size_t)w * 9) * HWn
                  + (size_t)(h0 + r) * Wn + (lh << 2);
#pragma unroll
  for (int dw = 0; dw < 9; ++dw) {
    float4 rz;
    rz.x = acc[dw].x * scale; rz.y = acc[dw].y * scale;
    rz.z = acc[dw].z * scale; rz.w = acc[dw].w * scale;
    *(float4*)(ob + (size_t)dw * HWn) = rz;
  }
}

extern "C" void kernel_launch(void* const* d_in, const int* in_sizes, int n_in,
                              void* d_out, int out_size, void* d_ws, size_t ws_size,
                              hipStream_t stream) {
  const float* x1 = (const float*)d_in[0];
  const float* x2 = (const float*)d_in[1];
  float* out = (float*)d_out;
  const int n_wgs = 8 * (Hn / TH);  // 512 WGs = 2 per CU
  corr_kernel<<<dim3(n_wgs), dim3(576), 0, stream>>>(x1, x2, out);
}